// Round 8
// baseline (711.316 us; speedup 1.0000x reference)
//
#include <hip/hip_runtime.h>

#define N_NODES   50000
#define N_EDGES   800000
#define NUM_GRAPHS 256
#define IN_FEAT   64
#define REL_DIM   32
#define HID       128
#define NUM_RELS  32
#define NUM_BASES 8
#define NUM_LAYERS 2

#define SCAN_BLKS ((N_NODES + 255) / 256)   // 196

typedef __attribute__((ext_vector_type(8))) short bf16x8;
typedef __attribute__((ext_vector_type(4))) float f32x4;

// async 16B global -> LDS (wave-uniform LDS base + lane*16; per-lane global src)
__device__ __forceinline__ void gld_lds16(void* lds, const void* g) {
    __builtin_amdgcn_global_load_lds(
        (const __attribute__((address_space(1))) unsigned int*)g,
        (__attribute__((address_space(3))) unsigned int*)lds, 16, 0, 0);
}

// ---------------- zero (float4 granularity) ----------------
__global__ void k_zero(float* __restrict__ p, int n4) {
    int i = blockIdx.x * 256 + threadIdx.x;
    if (i < n4) ((float4*)p)[i] = make_float4(0.f, 0.f, 0.f, 0.f);
}

// ---------------- CSR build: histogram, 3-phase scan, scatter ----------------
__global__ void k_hist(const int* __restrict__ dst, int* __restrict__ deg) {
    int e = blockIdx.x * 256 + threadIdx.x;
    if (e < N_EDGES) atomicAdd(&deg[dst[e]], 1);
}

__global__ void __launch_bounds__(256) k_scan_a(
    const int* __restrict__ deg, int* __restrict__ row_start, int* __restrict__ bsum) {
    __shared__ int s[256];
    int t = threadIdx.x;
    int idx = blockIdx.x * 256 + t;
    int v = (idx < N_NODES) ? deg[idx] : 0;
    s[t] = v;
    __syncthreads();
    for (int off = 1; off < 256; off <<= 1) {
        int u = (t >= off) ? s[t - off] : 0;
        __syncthreads();
        s[t] += u;
        __syncthreads();
    }
    if (idx < N_NODES) row_start[idx] = s[t] - v;   // local exclusive
    if (t == 255) bsum[blockIdx.x] = s[255];
}

__global__ void __launch_bounds__(256) k_scan_b(int* __restrict__ bsum,
                                                int* __restrict__ boff) {
    __shared__ int s[256];
    int t = threadIdx.x;
    int v = (t < SCAN_BLKS) ? bsum[t] : 0;
    s[t] = v;
    __syncthreads();
    for (int off = 1; off < 256; off <<= 1) {
        int u = (t >= off) ? s[t - off] : 0;
        __syncthreads();
        s[t] += u;
        __syncthreads();
    }
    if (t < SCAN_BLKS) boff[t] = s[t] - v;          // exclusive
}

__global__ void __launch_bounds__(256) k_scan_c(
    int* __restrict__ row_start, const int* __restrict__ boff,
    int* __restrict__ cursor) {
    int idx = blockIdx.x * 256 + threadIdx.x;
    if (idx < N_NODES) {
        int r = row_start[idx] + boff[blockIdx.x];
        row_start[idx] = r;
        cursor[idx] = r;
    }
    if (idx == 0) row_start[N_NODES] = N_EDGES;
}

__global__ void k_scatter(const int* __restrict__ src, const int* __restrict__ dst,
                          const int* __restrict__ ety, int* __restrict__ cursor,
                          int2* __restrict__ edge_s) {
    int e = blockIdx.x * 256 + threadIdx.x;
    if (e >= N_EDGES) return;
    int d = dst[e];
    int pos = atomicAdd(&cursor[d], 1);
    edge_s[pos] = make_int2(src[e], ety[e]);
}

// ---------------- input projection: h = relu([feat, er] @ W_in + b_in) ----------------
__global__ void __launch_bounds__(128) k_input(
    const float* __restrict__ feat, const int* __restrict__ qrel,
    const float* __restrict__ rel_emb, const float* __restrict__ Wi,
    const float* __restrict__ bi, float* __restrict__ h, float* __restrict__ er) {
    int n0 = blockIdx.x * 4;
    int j = threadIdx.x;
    int u = j >> 5, tt = j & 31;
    __shared__ float xT[96][4];
    xT[tt][u]      = feat[(size_t)(n0 + u) * IN_FEAT + tt];
    xT[tt + 32][u] = feat[(size_t)(n0 + u) * IN_FEAT + tt + 32];
    int qr = qrel[n0 + u];
    float e = rel_emb[qr * REL_DIM + tt];
    xT[64 + tt][u] = e;
    er[(size_t)(n0 + u) * REL_DIM + tt] = e;
    __syncthreads();
    float bj = bi[j];
    float a0 = bj, a1 = bj, a2 = bj, a3 = bj;
    for (int d = 0; d < 96; d++) {
        float4 xv = *(const float4*)&xT[d][0];
        float w = Wi[d * HID + j];
        a0 = fmaf(xv.x, w, a0); a1 = fmaf(xv.y, w, a1);
        a2 = fmaf(xv.z, w, a2); a3 = fmaf(xv.w, w, a3);
    }
    h[(size_t)(n0 + 0) * HID + j] = fmaxf(a0, 0.f);
    h[(size_t)(n0 + 1) * HID + j] = fmaxf(a1, 0.f);
    h[(size_t)(n0 + 2) * HID + j] = fmaxf(a2, 0.f);
    h[(size_t)(n0 + 3) * HID + j] = fmaxf(a3, 0.f);
}

// RNE f32 -> (hi bf16, lo bf16)
__device__ inline void rne_split(float f, unsigned short& hi, unsigned short& lo) {
    unsigned u = __builtin_bit_cast(unsigned, f);
    unsigned rh = (u + 0x7fffu + ((u >> 16) & 1u)) & 0xffff0000u;
    hi = (unsigned short)(rh >> 16);
    float fl = f - __builtin_bit_cast(float, rh);
    unsigned ul = __builtin_bit_cast(unsigned, fl);
    lo = (unsigned short)((ul + 0x7fffu + ((ul >> 16) & 1u)) >> 16);
}

// ---------------- per-dst basis-weighted gather, split-bf16 output ----------------
// Ghi/Glo[n-c0][b*128+d] = bf16-split of sum_e c[ety,b]*h[src,d]
__global__ void __launch_bounds__(256) k_mix2(
    const float* __restrict__ h, const float* __restrict__ comp_l,
    const int* __restrict__ row_start, const int2* __restrict__ edge_s,
    unsigned short* __restrict__ Ghi, unsigned short* __restrict__ Glo,
    int c0, int nc) {
    __shared__ float cs[NUM_RELS * NUM_BASES];
    if (threadIdx.x < NUM_RELS * NUM_BASES) cs[threadIdx.x] = comp_l[threadIdx.x];
    __syncthreads();
    int wave = threadIdx.x >> 6, lane = threadIdx.x & 63;
    int n = c0 + blockIdx.x * 4 + wave;
    if (n >= c0 + nc) return;
    int e0 = row_start[n], e1 = row_start[n + 1];
    float2 acc[NUM_BASES];
#pragma unroll
    for (int b = 0; b < NUM_BASES; b++) acc[b] = make_float2(0.f, 0.f);
    for (int e = e0; e < e1; e++) {
        int2 se = edge_s[e];
        const float* c = &cs[se.y * NUM_BASES];
        float2 v = ((const float2*)(h + (size_t)se.x * HID))[lane];
#pragma unroll
        for (int b = 0; b < NUM_BASES; b++) {
            acc[b].x = fmaf(c[b], v.x, acc[b].x);
            acc[b].y = fmaf(c[b], v.y, acc[b].y);
        }
    }
    size_t base = (size_t)(n - c0) * 1024 + 2 * lane;
#pragma unroll
    for (int b = 0; b < NUM_BASES; b++) {
        unsigned short hx, lx, hy, ly;
        rne_split(acc[b].x, hx, lx);
        rne_split(acc[b].y, hy, ly);
        *(ushort2*)&Ghi[base + b * 128] = make_ushort2(hx, hy);
        *(ushort2*)&Glo[base + b * 128] = make_ushort2(lx, ly);
    }
}

// ---------------- B fragment table: hi/lo bf16 of [Vl ; Wl] in MFMA fragment order ----------------
// entry (l, s, t, lane): 16 ushort = hi[8], lo[8];
// element j: B[k = s*32 + (lane>>4)*8 + j][col = t*16 + (lane&15)] of layer l.
__global__ void k_bfrag(const float* __restrict__ V, const float* __restrict__ W_loop,
                        unsigned short* __restrict__ Bf) {
    int idx = blockIdx.x * 256 + threadIdx.x;
    if (idx >= NUM_LAYERS * 36 * 8 * 64) return;
    int lane = idx & 63;
    int t = (idx >> 6) & 7;
    int s = (idx >> 9) % 36;
    int l = (idx >> 9) / 36;
    int col = t * 16 + (lane & 15);
    int kbase = s * 32 + (lane >> 4) * 8;
    unsigned short* o = Bf + (size_t)idx * 16;
#pragma unroll
    for (int j = 0; j < 8; j++) {
        int k = kbase + j;
        float f = (k < 1024) ? V[((size_t)l * 1024 + k) * HID + col]
                             : W_loop[((size_t)l * HID + (k - 1024)) * HID + col];
        unsigned short hi, lo;
        rne_split(f, hi, lo);
        o[j] = hi;
        o[8 + j] = lo;
    }
}

__device__ inline void split8(float4 a0, float4 a1, bf16x8& hi, bf16x8& lo) {
    float f[8] = {a0.x, a0.y, a0.z, a0.w, a1.x, a1.y, a1.z, a1.w};
#pragma unroll
    for (int j = 0; j < 8; j++) {
        unsigned short h, l;
        rne_split(f[j], h, l);
        hi[j] = (short)h;
        lo[j] = (short)l;
    }
}

// ---------------- MFMA GEMM, global_load_lds double-buffered A staging ----------------
// out = relu([G | h] @ [Vl ; Wl] + bl).  M=nc, K=1152, N=128.
// Block = 32 rows x 128 cols, 4 waves col-split (wave w -> t=2w,2w+1).
// A-tile (BK=64, hi+lo) staged in LDS in FRAGMENT ORDER, lane-linear ->
// conflict-free ds_read_b128. Wave w stages frags 2w,2w+1.
__global__ void __launch_bounds__(256) k_gemm5(
    const unsigned short* __restrict__ Ghi, const unsigned short* __restrict__ Glo,
    const float* __restrict__ h, const unsigned short* __restrict__ Bf,
    const float* __restrict__ bl, float* __restrict__ out, int c0, int nc) {
    __shared__ unsigned short smem[2][8][512];  // [buf][frag][1024 B]
    int lane = threadIdx.x & 63;
    int w = threadIdx.x >> 6;
    int rit = lane & 15, kg = lane >> 4;
    int r0 = blockIdx.x * 32;
    int st_i = w & 1, st_s = w >> 1;
    int st_row = r0 + st_i * 16 + rit; if (st_row >= nc) st_row = nc - 1;
    const unsigned short* gsh = Ghi + (size_t)st_row * 1024 + st_s * 32 + kg * 8;
    const unsigned short* gsl = Glo + (size_t)st_row * 1024 + st_s * 32 + kg * 8;
    const bf16x8* bb = (const bf16x8*)Bf + ((size_t)(2 * w) * 64 + lane) * 2;
    f32x4 acc00 = {}, acc01 = {}, acc10 = {}, acc11 = {};

#define MM(AH, AL, BH, BL, ACC) {                                        \
        ACC = __builtin_amdgcn_mfma_f32_16x16x32_bf16(AH, BH, ACC, 0, 0, 0); \
        ACC = __builtin_amdgcn_mfma_f32_16x16x32_bf16(AL, BH, ACC, 0, 0, 0); \
        ACC = __builtin_amdgcn_mfma_f32_16x16x32_bf16(AH, BL, ACC, 0, 0, 0); }
#define STAGE(BUF, STEP) {                                   \
        gld_lds16(&smem[BUF][2 * w + 0][0], gsh + (STEP) * 64); \
        gld_lds16(&smem[BUF][2 * w + 1][0], gsl + (STEP) * 64); }
#define CSTEP(BUF, STEP) _Pragma("unroll")                              \
    for (int s = 0; s < 2; s++) {                                       \
        const bf16x8* bp = bb + (size_t)((STEP) * 2 + s) * 1024;        \
        bf16x8 bh0 = bp[0], bq0 = bp[1], bh1 = bp[128], bq1 = bp[129];  \
        bf16x8 a0h = *(const bf16x8*)&smem[BUF][(s * 2 + 0) * 2 + 0][lane * 8]; \
        bf16x8 a0l = *(const bf16x8*)&smem[BUF][(s * 2 + 0) * 2 + 1][lane * 8]; \
        bf16x8 a1h = *(const bf16x8*)&smem[BUF][(s * 2 + 1) * 2 + 0][lane * 8]; \
        bf16x8 a1l = *(const bf16x8*)&smem[BUF][(s * 2 + 1) * 2 + 1][lane * 8]; \
        MM(a0h, a0l, bh0, bq0, acc00); MM(a0h, a0l, bh1, bq1, acc01);   \
        MM(a1h, a1l, bh0, bq0, acc10); MM(a1h, a1l, bh1, bq1, acc11);   \
    }

    STAGE(0, 0);
    for (int t = 0; t < 16; t++) {
        __syncthreads();
        if (t < 15) STAGE((t + 1) & 1, t + 1);
        CSTEP(t & 1, t);
    }
    // K tail 1024..1151 from f32 h, split on the fly (4 k-subtiles)
    int rT0 = r0 + rit;      if (rT0 >= nc) rT0 = nc - 1;
    int rT1 = r0 + 16 + rit; if (rT1 >= nc) rT1 = nc - 1;
    const float* hp0 = h + (size_t)(c0 + rT0) * HID + kg * 8;
    const float* hp1 = h + (size_t)(c0 + rT1) * HID + kg * 8;
#pragma unroll
    for (int s = 32; s < 36; s++) {
        int o = (s - 32) * 32;
        bf16x8 a0h, a0l, a1h, a1l;
        split8(*(const float4*)(hp0 + o), *(const float4*)(hp0 + o + 4), a0h, a0l);
        split8(*(const float4*)(hp1 + o), *(const float4*)(hp1 + o + 4), a1h, a1l);
        const bf16x8* bp = bb + (size_t)s * 1024;
        bf16x8 bh0 = bp[0], bq0 = bp[1], bh1 = bp[128], bq1 = bp[129];
        MM(a0h, a0l, bh0, bq0, acc00); MM(a0h, a0l, bh1, bq1, acc01);
        MM(a1h, a1l, bh0, bq0, acc10); MM(a1h, a1l, bh1, bq1, acc11);
    }
#undef MM
#undef STAGE
#undef CSTEP
    int col0 = 2 * w * 16 + rit;
    float b0 = bl[col0], b1 = bl[col0 + 16];
    int rq = r0 + kg * 4;
#pragma unroll
    for (int q = 0; q < 4; q++) {
        int rA = rq + q;
        if (rA < nc) {
            out[(size_t)(c0 + rA) * HID + col0]      = fmaxf(acc00[q] + b0, 0.f);
            out[(size_t)(c0 + rA) * HID + col0 + 16] = fmaxf(acc01[q] + b1, 0.f);
        }
        int rB = rA + 16;
        if (rB < nc) {
            out[(size_t)(c0 + rB) * HID + col0]      = fmaxf(acc10[q] + b0, 0.f);
            out[(size_t)(c0 + rB) * HID + col0 + 16] = fmaxf(acc11[q] + b1, 0.f);
        }
    }
}

// ---------------- attention scalar score per node ----------------
__global__ void __launch_bounds__(128) k_score(
    const float* __restrict__ h, const float* __restrict__ er,
    const float* __restrict__ Wa, const float* __restrict__ ba,
    const float* __restrict__ wsc, const float* __restrict__ bsc,
    float* __restrict__ a) {
    int n0 = blockIdx.x * 4;
    int j = threadIdx.x;
    int u = j >> 5, tt = j & 31;
    __shared__ float xT[160][4];
#pragma unroll
    for (int c = 0; c < 4; c++)
        xT[tt + 32 * c][u] = h[(size_t)(n0 + u) * HID + tt + 32 * c];
    xT[128 + tt][u] = er[(size_t)(n0 + u) * REL_DIM + tt];
    __syncthreads();
    float bj = ba[j];
    float a0 = bj, a1 = bj, a2 = bj, a3 = bj;
    for (int d = 0; d < 160; d++) {
        float4 xv = *(const float4*)&xT[d][0];
        float w = Wa[d * HID + j];
        a0 = fmaf(xv.x, w, a0); a1 = fmaf(xv.y, w, a1);
        a2 = fmaf(xv.z, w, a2); a3 = fmaf(xv.w, w, a3);
    }
    float wj = wsc[j];
    __shared__ float red[4][128];
    red[0][j] = tanhf(a0) * wj;
    red[1][j] = tanhf(a1) * wj;
    red[2][j] = tanhf(a2) * wj;
    red[3][j] = tanhf(a3) * wj;
    __syncthreads();
    for (int s = 64; s > 0; s >>= 1) {
        if (j < s) {
            red[0][j] += red[0][j + s];
            red[1][j] += red[1][j + s];
            red[2][j] += red[2][j + s];
            red[3][j] += red[3][j + s];
        }
        __syncthreads();
    }
    if (j < 4) a[n0 + j] = red[j][0] + bsc[0];
}

// ---------------- graph boundaries (graph_id is sorted) ----------------
__global__ void k_starts(const int* __restrict__ gid, int* __restrict__ starts) {
    int g = threadIdx.x;  // 0..255
    int lo = 0, hi = N_NODES;
    while (lo < hi) {
        int mid = (lo + hi) >> 1;
        if (gid[mid] < g) lo = mid + 1; else hi = mid;
    }
    starts[g] = lo;
    if (g == 0) starts[NUM_GRAPHS] = N_NODES;
}

// ---------------- segment softmax pooling + final dot ----------------
__global__ void __launch_bounds__(128) k_pool(
    const float* __restrict__ h, const float* __restrict__ a,
    const int* __restrict__ starts, const float* __restrict__ wout,
    const float* __restrict__ bout, float* __restrict__ out) {
    int g = blockIdx.x, j = threadIdx.x;
    int s0 = starts[g], s1 = starts[g + 1];
    __shared__ float red[128];
    __shared__ float exb[128];
    if (s1 <= s0) { if (j == 0) out[g] = bout[0]; return; }
    float m = -3.4e38f;
    for (int i = s0 + j; i < s1; i += 128) m = fmaxf(m, a[i]);
    red[j] = m; __syncthreads();
    for (int s = 64; s > 0; s >>= 1) {
        if (j < s) red[j] = fmaxf(red[j], red[j + s]);
        __syncthreads();
    }
    m = red[0]; __syncthreads();
    float zj = 0.f, ss = 0.f;
    for (int base = s0; base < s1; base += 128) {
        int cnt = min(128, s1 - base);
        float ev = 0.f;
        if (j < cnt) ev = expf(a[base + j] - m);
        exb[j] = ev;
        ss += ev;
        __syncthreads();
        for (int k = 0; k < cnt; k++)
            zj = fmaf(exb[k], h[(size_t)(base + k) * HID + j], zj);
        __syncthreads();
    }
    red[j] = ss; __syncthreads();
    for (int s = 64; s > 0; s >>= 1) {
        if (j < s) red[j] += red[j + s];
        __syncthreads();
    }
    ss = red[0]; __syncthreads();
    red[j] = (zj / ss) * wout[j]; __syncthreads();
    for (int s = 64; s > 0; s >>= 1) {
        if (j < s) red[j] += red[j + s];
        __syncthreads();
    }
    if (j == 0) out[g] = red[0] + bout[0];
}

extern "C" void kernel_launch(void* const* d_in, const int* in_sizes, int n_in,
                              void* d_out, int out_size, void* d_ws, size_t ws_size,
                              hipStream_t stream) {
    const float* feat    = (const float*)d_in[0];
    const int*   qrel    = (const int*)d_in[1];
    const int*   src     = (const int*)d_in[2];
    const int*   dst     = (const int*)d_in[3];
    const int*   ety     = (const int*)d_in[4];
    const int*   gid     = (const int*)d_in[5];
    const float* rel_emb = (const float*)d_in[6];
    const float* W_in    = (const float*)d_in[7];
    const float* b_in    = (const float*)d_in[8];
    const float* V       = (const float*)d_in[9];
    const float* comp    = (const float*)d_in[10];
    const float* W_loop  = (const float*)d_in[11];
    const float* b_loop  = (const float*)d_in[12];
    const float* W_attn  = (const float*)d_in[13];
    const float* b_attn  = (const float*)d_in[14];
    const float* w_sc    = (const float*)d_in[15];
    const float* b_sc    = (const float*)d_in[16];
    const float* w_out   = (const float*)d_in[17];
    const float* b_out   = (const float*)d_in[18];
    float* out = (float*)d_out;

    float* ws = (float*)d_ws;
    float* h0 = ws;                                   // 6.4M floats
    float* h1 = h0 + (size_t)N_NODES * HID;           // 6.4M
    float* er = h1 + (size_t)N_NODES * HID;           // 1.6M
    float* af = er + (size_t)N_NODES * REL_DIM;       // 50000
    int* starts    = (int*)(af + N_NODES);            // 260
    int* deg       = starts + 260;                    // 50000
    int* row_start = deg + 50000;                     // 50004
    int* cursor    = row_start + 50004;               // 50000
    int* bsum      = cursor + 50000;                  // 256
    int* boff      = bsum + 256;                      // 256
    int2* edge_s   = (int2*)(boff + 256);             // 800000 int2
    unsigned short* Bf = (unsigned short*)(edge_s + 800000);  // 2*36*8*64*16 ushort
    const size_t BF_USHORT = (size_t)NUM_LAYERS * 36 * 8 * 64 * 16;
    unsigned short* Ghi = Bf + BF_USHORT;

    size_t used_floats = (size_t)((float*)Ghi - ws);
    size_t total_floats = ws_size / sizeof(float);
    size_t avail = (total_floats > used_floats) ? (total_floats - used_floats) : 0;
    long long NC = (long long)(avail / 1024);         // rows: 1024 hi + 1024 lo ushorts = 1024 floats
    NC = (NC / 64) * 64;
    if (NC > 16384) NC = 16384;   // L3-resident G chunk (64 MB hi+lo)
    if (NC < 64) NC = 64;
    unsigned short* Glo = Ghi + (size_t)NC * 1024;

    // --- preprocessing ---
    k_zero<<<(12500 + 255) / 256, 256, 0, stream>>>((float*)deg, 12500);
    k_hist<<<(N_EDGES + 255) / 256, 256, 0, stream>>>(dst, deg);
    k_scan_a<<<SCAN_BLKS, 256, 0, stream>>>(deg, row_start, bsum);
    k_scan_b<<<1, 256, 0, stream>>>(bsum, boff);
    k_scan_c<<<SCAN_BLKS, 256, 0, stream>>>(row_start, boff, cursor);
    k_scatter<<<(N_EDGES + 255) / 256, 256, 0, stream>>>(src, dst, ety, cursor, edge_s);
    k_bfrag<<<(NUM_LAYERS * 36 * 8 * 64 + 255) / 256, 256, 0, stream>>>(V, W_loop, Bf);
    k_input<<<N_NODES / 4, 128, 0, stream>>>(feat, qrel, rel_emb, W_in, b_in, h0, er);

    float* hcur = h0;
    float* hnext = h1;
    for (int l = 0; l < NUM_LAYERS; l++) {
        const float* comp_l = comp + (size_t)l * NUM_RELS * NUM_BASES;
        const unsigned short* Bfl = Bf + (size_t)l * 36 * 8 * 64 * 16;
        const float* bl = b_loop + (size_t)l * HID;
        for (int c0 = 0; c0 < N_NODES; c0 += (int)NC) {
            int nc = (int)((N_NODES - c0 < NC) ? (N_NODES - c0) : NC);
            k_mix2<<<(nc + 3) / 4, 256, 0, stream>>>(hcur, comp_l, row_start, edge_s,
                                                     Ghi, Glo, c0, nc);
            k_gemm5<<<(nc + 31) / 32, 256, 0, stream>>>(Ghi, Glo, hcur, Bfl, bl,
                                                        hnext, c0, nc);
        }
        float* tmp = hcur; hcur = hnext; hnext = tmp;
    }

    k_score<<<N_NODES / 4, 128, 0, stream>>>(hcur, er, W_attn, b_attn, w_sc, b_sc, af);
    k_starts<<<1, 256, 0, stream>>>(gid, starts);
    k_pool<<<NUM_GRAPHS, 128, 0, stream>>>(hcur, af, starts, w_out, b_out, out);
}

// Round 9
// 593.660 us; speedup vs baseline: 1.1982x; 1.1982x over previous
//
#include <hip/hip_runtime.h>

#define N_NODES   50000
#define N_EDGES   800000
#define NUM_GRAPHS 256
#define IN_FEAT   64
#define REL_DIM   32
#define HID       128
#define NUM_RELS  32
#define NUM_BASES 8
#define NUM_LAYERS 2

#define SCAN_BLKS ((N_NODES + 255) / 256)   // 196

typedef __attribute__((ext_vector_type(8))) short bf16x8;
typedef __attribute__((ext_vector_type(4))) float f32x4;

// async 16B global -> LDS (wave-uniform LDS base + lane*16; per-lane global src)
__device__ __forceinline__ void gld_lds16(void* lds, const void* g) {
    __builtin_amdgcn_global_load_lds(
        (const __attribute__((address_space(1))) unsigned int*)g,
        (__attribute__((address_space(3))) unsigned int*)lds, 16, 0, 0);
}

// ---------------- zero (float4 granularity) ----------------
__global__ void k_zero(float* __restrict__ p, int n4) {
    int i = blockIdx.x * 256 + threadIdx.x;
    if (i < n4) ((float4*)p)[i] = make_float4(0.f, 0.f, 0.f, 0.f);
}

// ---------------- CSR build: histogram, 3-phase scan, scatter ----------------
__global__ void k_hist(const int* __restrict__ dst, int* __restrict__ deg) {
    int e = blockIdx.x * 256 + threadIdx.x;
    if (e < N_EDGES) atomicAdd(&deg[dst[e]], 1);
}

__global__ void __launch_bounds__(256) k_scan_a(
    const int* __restrict__ deg, int* __restrict__ row_start, int* __restrict__ bsum) {
    __shared__ int s[256];
    int t = threadIdx.x;
    int idx = blockIdx.x * 256 + t;
    int v = (idx < N_NODES) ? deg[idx] : 0;
    s[t] = v;
    __syncthreads();
    for (int off = 1; off < 256; off <<= 1) {
        int u = (t >= off) ? s[t - off] : 0;
        __syncthreads();
        s[t] += u;
        __syncthreads();
    }
    if (idx < N_NODES) row_start[idx] = s[t] - v;   // local exclusive
    if (t == 255) bsum[blockIdx.x] = s[255];
}

__global__ void __launch_bounds__(256) k_scan_b(int* __restrict__ bsum,
                                                int* __restrict__ boff) {
    __shared__ int s[256];
    int t = threadIdx.x;
    int v = (t < SCAN_BLKS) ? bsum[t] : 0;
    s[t] = v;
    __syncthreads();
    for (int off = 1; off < 256; off <<= 1) {
        int u = (t >= off) ? s[t - off] : 0;
        __syncthreads();
        s[t] += u;
        __syncthreads();
    }
    if (t < SCAN_BLKS) boff[t] = s[t] - v;          // exclusive
}

__global__ void __launch_bounds__(256) k_scan_c(
    int* __restrict__ row_start, const int* __restrict__ boff,
    int* __restrict__ cursor) {
    int idx = blockIdx.x * 256 + threadIdx.x;
    if (idx < N_NODES) {
        int r = row_start[idx] + boff[blockIdx.x];
        row_start[idx] = r;
        cursor[idx] = r;
    }
    if (idx == 0) row_start[N_NODES] = N_EDGES;
}

// packed payload: (src << 5) | ety   (src < 2^17, ety < 32)
__global__ void k_scatter(const int* __restrict__ src, const int* __restrict__ dst,
                          const int* __restrict__ ety, int* __restrict__ cursor,
                          int* __restrict__ edge_p) {
    int e = blockIdx.x * 256 + threadIdx.x;
    if (e >= N_EDGES) return;
    int d = dst[e];
    int pos = atomicAdd(&cursor[d], 1);
    edge_p[pos] = (src[e] << 5) | ety[e];
}

// ---------------- input projection (16 nodes/block): h = relu([feat, er] @ W_in + b_in) ----------------
__global__ void __launch_bounds__(128) k_input(
    const float* __restrict__ feat, const int* __restrict__ qrel,
    const float* __restrict__ rel_emb, const float* __restrict__ Wi,
    const float* __restrict__ bi, float* __restrict__ h, float* __restrict__ er) {
    int n0 = blockIdx.x * 16;
    int j = threadIdx.x;
    int u = j >> 3, q = j & 7;
    __shared__ float xT[96][16];
    {
        const float4* f4 = (const float4*)(feat + (size_t)(n0 + u) * IN_FEAT);
        float4 a = f4[q], b = f4[q + 8];
        xT[4 * q + 0][u] = a.x; xT[4 * q + 1][u] = a.y;
        xT[4 * q + 2][u] = a.z; xT[4 * q + 3][u] = a.w;
        xT[32 + 4 * q + 0][u] = b.x; xT[32 + 4 * q + 1][u] = b.y;
        xT[32 + 4 * q + 2][u] = b.z; xT[32 + 4 * q + 3][u] = b.w;
        int qr = qrel[n0 + u];
        float4 e4 = ((const float4*)(rel_emb + (size_t)qr * REL_DIM))[q];
        xT[64 + 4 * q + 0][u] = e4.x; xT[64 + 4 * q + 1][u] = e4.y;
        xT[64 + 4 * q + 2][u] = e4.z; xT[64 + 4 * q + 3][u] = e4.w;
        ((float4*)(er + (size_t)(n0 + u) * REL_DIM))[q] = e4;
    }
    __syncthreads();
    float bj = bi[j];
    float acc[16];
#pragma unroll
    for (int k = 0; k < 16; k++) acc[k] = bj;
    for (int d = 0; d < 96; d++) {
        float w = Wi[d * HID + j];
        float4 x0 = *(const float4*)&xT[d][0];
        float4 x1 = *(const float4*)&xT[d][4];
        float4 x2 = *(const float4*)&xT[d][8];
        float4 x3 = *(const float4*)&xT[d][12];
        acc[0]  = fmaf(x0.x, w, acc[0]);  acc[1]  = fmaf(x0.y, w, acc[1]);
        acc[2]  = fmaf(x0.z, w, acc[2]);  acc[3]  = fmaf(x0.w, w, acc[3]);
        acc[4]  = fmaf(x1.x, w, acc[4]);  acc[5]  = fmaf(x1.y, w, acc[5]);
        acc[6]  = fmaf(x1.z, w, acc[6]);  acc[7]  = fmaf(x1.w, w, acc[7]);
        acc[8]  = fmaf(x2.x, w, acc[8]);  acc[9]  = fmaf(x2.y, w, acc[9]);
        acc[10] = fmaf(x2.z, w, acc[10]); acc[11] = fmaf(x2.w, w, acc[11]);
        acc[12] = fmaf(x3.x, w, acc[12]); acc[13] = fmaf(x3.y, w, acc[13]);
        acc[14] = fmaf(x3.z, w, acc[14]); acc[15] = fmaf(x3.w, w, acc[15]);
    }
#pragma unroll
    for (int k = 0; k < 16; k++)
        h[(size_t)(n0 + k) * HID + j] = fmaxf(acc[k], 0.f);
}

// RNE f32 -> (hi bf16, lo bf16)
__device__ inline void rne_split(float f, unsigned short& hi, unsigned short& lo) {
    unsigned u = __builtin_bit_cast(unsigned, f);
    unsigned rh = (u + 0x7fffu + ((u >> 16) & 1u)) & 0xffff0000u;
    hi = (unsigned short)(rh >> 16);
    float fl = f - __builtin_bit_cast(float, rh);
    unsigned ul = __builtin_bit_cast(unsigned, fl);
    lo = (unsigned short)((ul + 0x7fffu + ((ul >> 16) & 1u)) >> 16);
}

// ---------------- per-dst basis-weighted gather, split-bf16 output ----------------
// Ghi/Glo[n-c0][b*128+d] = bf16-split of sum_e c[ety,b]*h[src,d]
__global__ void __launch_bounds__(256) k_mix2(
    const float* __restrict__ h, const float* __restrict__ comp_l,
    const int* __restrict__ row_start, const int* __restrict__ edge_p,
    unsigned short* __restrict__ Ghi, unsigned short* __restrict__ Glo,
    int c0, int nc) {
    __shared__ float cs[NUM_RELS * NUM_BASES];
    if (threadIdx.x < NUM_RELS * NUM_BASES) cs[threadIdx.x] = comp_l[threadIdx.x];
    __syncthreads();
    int wave = threadIdx.x >> 6, lane = threadIdx.x & 63;
    int n = c0 + blockIdx.x * 4 + wave;
    if (n >= c0 + nc) return;
    int e0 = row_start[n], e1 = row_start[n + 1];
    float2 acc[NUM_BASES];
#pragma unroll
    for (int b = 0; b < NUM_BASES; b++) acc[b] = make_float2(0.f, 0.f);
    for (int e = e0; e < e1; e++) {
        int se = edge_p[e];
        const float* c = &cs[(se & 31) * NUM_BASES];
        float2 v = ((const float2*)(h + (size_t)(se >> 5) * HID))[lane];
#pragma unroll
        for (int b = 0; b < NUM_BASES; b++) {
            acc[b].x = fmaf(c[b], v.x, acc[b].x);
            acc[b].y = fmaf(c[b], v.y, acc[b].y);
        }
    }
    size_t base = (size_t)(n - c0) * 1024 + 2 * lane;
#pragma unroll
    for (int b = 0; b < NUM_BASES; b++) {
        unsigned short hx, lx, hy, ly;
        rne_split(acc[b].x, hx, lx);
        rne_split(acc[b].y, hy, ly);
        *(ushort2*)&Ghi[base + b * 128] = make_ushort2(hx, hy);
        *(ushort2*)&Glo[base + b * 128] = make_ushort2(lx, ly);
    }
}

// ---------------- B fragment table: hi/lo bf16 of [Vl ; Wl] in MFMA fragment order ----------------
// entry (l, s, t, lane): 16 ushort = hi[8], lo[8];
// element j: B[k = s*32 + (lane>>4)*8 + j][col = t*16 + (lane&15)] of layer l.
__global__ void k_bfrag(const float* __restrict__ V, const float* __restrict__ W_loop,
                        unsigned short* __restrict__ Bf) {
    int idx = blockIdx.x * 256 + threadIdx.x;
    if (idx >= NUM_LAYERS * 36 * 8 * 64) return;
    int lane = idx & 63;
    int t = (idx >> 6) & 7;
    int s = (idx >> 9) % 36;
    int l = (idx >> 9) / 36;
    int col = t * 16 + (lane & 15);
    int kbase = s * 32 + (lane >> 4) * 8;
    unsigned short* o = Bf + (size_t)idx * 16;
#pragma unroll
    for (int j = 0; j < 8; j++) {
        int k = kbase + j;
        float f = (k < 1024) ? V[((size_t)l * 1024 + k) * HID + col]
                             : W_loop[((size_t)l * HID + (k - 1024)) * HID + col];
        unsigned short hi, lo;
        rne_split(f, hi, lo);
        o[j] = hi;
        o[8 + j] = lo;
    }
}

__device__ inline void split8(float4 a0, float4 a1, bf16x8& hi, bf16x8& lo) {
    float f[8] = {a0.x, a0.y, a0.z, a0.w, a1.x, a1.y, a1.z, a1.w};
#pragma unroll
    for (int j = 0; j < 8; j++) {
        unsigned short h, l;
        rne_split(f[j], h, l);
        hi[j] = (short)h;
        lo[j] = (short)l;
    }
}

// ---------------- MFMA GEMM, global_load_lds double-buffered A staging ----------------
// out = relu([G | h] @ [Vl ; Wl] + bl).  M=nc, K=1152, N=128.
// Block = 32 rows x 128 cols, 4 waves col-split (wave w -> t=2w,2w+1).
// A-tile (BK=64, hi+lo) staged in LDS in FRAGMENT ORDER, lane-linear ->
// conflict-free ds_read_b128. Wave w stages frags 2w,2w+1.
__global__ void __launch_bounds__(256) k_gemm5(
    const unsigned short* __restrict__ Ghi, const unsigned short* __restrict__ Glo,
    const float* __restrict__ h, const unsigned short* __restrict__ Bf,
    const float* __restrict__ bl, float* __restrict__ out, int c0, int nc) {
    __shared__ unsigned short smem[2][8][512];  // [buf][frag][1024 B]
    int lane = threadIdx.x & 63;
    int w = threadIdx.x >> 6;
    int rit = lane & 15, kg = lane >> 4;
    int r0 = blockIdx.x * 32;
    int st_i = w & 1, st_s = w >> 1;
    int st_row = r0 + st_i * 16 + rit; if (st_row >= nc) st_row = nc - 1;
    const unsigned short* gsh = Ghi + (size_t)st_row * 1024 + st_s * 32 + kg * 8;
    const unsigned short* gsl = Glo + (size_t)st_row * 1024 + st_s * 32 + kg * 8;
    const bf16x8* bb = (const bf16x8*)Bf + ((size_t)(2 * w) * 64 + lane) * 2;
    f32x4 acc00 = {}, acc01 = {}, acc10 = {}, acc11 = {};

#define MM(AH, AL, BH, BL, ACC) {                                        \
        ACC = __builtin_amdgcn_mfma_f32_16x16x32_bf16(AH, BH, ACC, 0, 0, 0); \
        ACC = __builtin_amdgcn_mfma_f32_16x16x32_bf16(AL, BH, ACC, 0, 0, 0); \
        ACC = __builtin_amdgcn_mfma_f32_16x16x32_bf16(AH, BL, ACC, 0, 0, 0); }
#define STAGE(BUF, STEP) {                                   \
        gld_lds16(&smem[BUF][2 * w + 0][0], gsh + (STEP) * 64); \
        gld_lds16(&smem[BUF][2 * w + 1][0], gsl + (STEP) * 64); }
#define CSTEP(BUF, STEP) _Pragma("unroll")                              \
    for (int s = 0; s < 2; s++) {                                       \
        const bf16x8* bp = bb + (size_t)((STEP) * 2 + s) * 1024;        \
        bf16x8 bh0 = bp[0], bq0 = bp[1], bh1 = bp[128], bq1 = bp[129];  \
        bf16x8 a0h = *(const bf16x8*)&smem[BUF][(s * 2 + 0) * 2 + 0][lane * 8]; \
        bf16x8 a0l = *(const bf16x8*)&smem[BUF][(s * 2 + 0) * 2 + 1][lane * 8]; \
        bf16x8 a1h = *(const bf16x8*)&smem[BUF][(s * 2 + 1) * 2 + 0][lane * 8]; \
        bf16x8 a1l = *(const bf16x8*)&smem[BUF][(s * 2 + 1) * 2 + 1][lane * 8]; \
        MM(a0h, a0l, bh0, bq0, acc00); MM(a0h, a0l, bh1, bq1, acc01);   \
        MM(a1h, a1l, bh0, bq0, acc10); MM(a1h, a1l, bh1, bq1, acc11);   \
    }

    STAGE(0, 0);
    for (int t = 0; t < 16; t++) {
        __syncthreads();
        if (t < 15) STAGE((t + 1) & 1, t + 1);
        CSTEP(t & 1, t);
    }
    // K tail 1024..1151 from f32 h, split on the fly (4 k-subtiles)
    int rT0 = r0 + rit;      if (rT0 >= nc) rT0 = nc - 1;
    int rT1 = r0 + 16 + rit; if (rT1 >= nc) rT1 = nc - 1;
    const float* hp0 = h + (size_t)(c0 + rT0) * HID + kg * 8;
    const float* hp1 = h + (size_t)(c0 + rT1) * HID + kg * 8;
#pragma unroll
    for (int s = 32; s < 36; s++) {
        int o = (s - 32) * 32;
        bf16x8 a0h, a0l, a1h, a1l;
        split8(*(const float4*)(hp0 + o), *(const float4*)(hp0 + o + 4), a0h, a0l);
        split8(*(const float4*)(hp1 + o), *(const float4*)(hp1 + o + 4), a1h, a1l);
        const bf16x8* bp = bb + (size_t)s * 1024;
        bf16x8 bh0 = bp[0], bq0 = bp[1], bh1 = bp[128], bq1 = bp[129];
        MM(a0h, a0l, bh0, bq0, acc00); MM(a0h, a0l, bh1, bq1, acc01);
        MM(a1h, a1l, bh0, bq0, acc10); MM(a1h, a1l, bh1, bq1, acc11);
    }
#undef MM
#undef STAGE
#undef CSTEP
    int col0 = 2 * w * 16 + rit;
    float b0 = bl[col0], b1 = bl[col0 + 16];
    int rq = r0 + kg * 4;
#pragma unroll
    for (int q = 0; q < 4; q++) {
        int rA = rq + q;
        if (rA < nc) {
            out[(size_t)(c0 + rA) * HID + col0]      = fmaxf(acc00[q] + b0, 0.f);
            out[(size_t)(c0 + rA) * HID + col0 + 16] = fmaxf(acc01[q] + b1, 0.f);
        }
        int rB = rA + 16;
        if (rB < nc) {
            out[(size_t)(c0 + rB) * HID + col0]      = fmaxf(acc10[q] + b0, 0.f);
            out[(size_t)(c0 + rB) * HID + col0 + 16] = fmaxf(acc11[q] + b1, 0.f);
        }
    }
}

// ---------------- attention scalar score per node (16 nodes/block) ----------------
__global__ void __launch_bounds__(128) k_score(
    const float* __restrict__ h, const float* __restrict__ er,
    const float* __restrict__ Wa, const float* __restrict__ ba,
    const float* __restrict__ wsc, const float* __restrict__ bsc,
    float* __restrict__ a) {
    int n0 = blockIdx.x * 16;
    int j = threadIdx.x;
    int u = j >> 3, q = j & 7;
    __shared__ float xT[160][16];
    {
        const float4* h4 = (const float4*)(h + (size_t)(n0 + u) * HID);
#pragma unroll
        for (int k = 0; k < 4; k++) {
            float4 v = h4[q + 8 * k];
            xT[32 * k + 4 * q + 0][u] = v.x; xT[32 * k + 4 * q + 1][u] = v.y;
            xT[32 * k + 4 * q + 2][u] = v.z; xT[32 * k + 4 * q + 3][u] = v.w;
        }
        float4 e4 = ((const float4*)(er + (size_t)(n0 + u) * REL_DIM))[q];
        xT[128 + 4 * q + 0][u] = e4.x; xT[128 + 4 * q + 1][u] = e4.y;
        xT[128 + 4 * q + 2][u] = e4.z; xT[128 + 4 * q + 3][u] = e4.w;
    }
    __syncthreads();
    float bj = ba[j];
    float acc[16];
#pragma unroll
    for (int k = 0; k < 16; k++) acc[k] = bj;
    for (int d = 0; d < 160; d++) {
        float w = Wa[d * HID + j];
        float4 x0 = *(const float4*)&xT[d][0];
        float4 x1 = *(const float4*)&xT[d][4];
        float4 x2 = *(const float4*)&xT[d][8];
        float4 x3 = *(const float4*)&xT[d][12];
        acc[0]  = fmaf(x0.x, w, acc[0]);  acc[1]  = fmaf(x0.y, w, acc[1]);
        acc[2]  = fmaf(x0.z, w, acc[2]);  acc[3]  = fmaf(x0.w, w, acc[3]);
        acc[4]  = fmaf(x1.x, w, acc[4]);  acc[5]  = fmaf(x1.y, w, acc[5]);
        acc[6]  = fmaf(x1.z, w, acc[6]);  acc[7]  = fmaf(x1.w, w, acc[7]);
        acc[8]  = fmaf(x2.x, w, acc[8]);  acc[9]  = fmaf(x2.y, w, acc[9]);
        acc[10] = fmaf(x2.z, w, acc[10]); acc[11] = fmaf(x2.w, w, acc[11]);
        acc[12] = fmaf(x3.x, w, acc[12]); acc[13] = fmaf(x3.y, w, acc[13]);
        acc[14] = fmaf(x3.z, w, acc[14]); acc[15] = fmaf(x3.w, w, acc[15]);
    }
    __shared__ float red[16][128];
    float wj = wsc[j];
#pragma unroll
    for (int k = 0; k < 16; k++) red[k][j] = tanhf(acc[k]) * wj;
    __syncthreads();
    for (int s = 64; s > 0; s >>= 1) {
        if (j < s) {
#pragma unroll
            for (int k = 0; k < 16; k++) red[k][j] += red[k][j + s];
        }
        __syncthreads();
    }
    if (j < 16) a[n0 + j] = red[j][0] + bsc[0];
}

// ---------------- graph boundaries (graph_id is sorted) ----------------
__global__ void k_starts(const int* __restrict__ gid, int* __restrict__ starts) {
    int g = threadIdx.x;  // 0..255
    int lo = 0, hi = N_NODES;
    while (lo < hi) {
        int mid = (lo + hi) >> 1;
        if (gid[mid] < g) lo = mid + 1; else hi = mid;
    }
    starts[g] = lo;
    if (g == 0) starts[NUM_GRAPHS] = N_NODES;
}

// ---------------- segment softmax pooling + final dot ----------------
__global__ void __launch_bounds__(128) k_pool(
    const float* __restrict__ h, const float* __restrict__ a,
    const int* __restrict__ starts, const float* __restrict__ wout,
    const float* __restrict__ bout, float* __restrict__ out) {
    int g = blockIdx.x, j = threadIdx.x;
    int s0 = starts[g], s1 = starts[g + 1];
    __shared__ float red[128];
    __shared__ float exb[128];
    if (s1 <= s0) { if (j == 0) out[g] = bout[0]; return; }
    float m = -3.4e38f;
    for (int i = s0 + j; i < s1; i += 128) m = fmaxf(m, a[i]);
    red[j] = m; __syncthreads();
    for (int s = 64; s > 0; s >>= 1) {
        if (j < s) red[j] = fmaxf(red[j], red[j + s]);
        __syncthreads();
    }
    m = red[0]; __syncthreads();
    float zj = 0.f, ss = 0.f;
    for (int base = s0; base < s1; base += 128) {
        int cnt = min(128, s1 - base);
        float ev = 0.f;
        if (j < cnt) ev = expf(a[base + j] - m);
        exb[j] = ev;
        ss += ev;
        __syncthreads();
        for (int k = 0; k < cnt; k++)
            zj = fmaf(exb[k], h[(size_t)(base + k) * HID + j], zj);
        __syncthreads();
    }
    red[j] = ss; __syncthreads();
    for (int s = 64; s > 0; s >>= 1) {
        if (j < s) red[j] += red[j + s];
        __syncthreads();
    }
    ss = red[0]; __syncthreads();
    red[j] = (zj / ss) * wout[j]; __syncthreads();
    for (int s = 64; s > 0; s >>= 1) {
        if (j < s) red[j] += red[j + s];
        __syncthreads();
    }
    if (j == 0) out[g] = red[0] + bout[0];
}

extern "C" void kernel_launch(void* const* d_in, const int* in_sizes, int n_in,
                              void* d_out, int out_size, void* d_ws, size_t ws_size,
                              hipStream_t stream) {
    const float* feat    = (const float*)d_in[0];
    const int*   qrel    = (const int*)d_in[1];
    const int*   src     = (const int*)d_in[2];
    const int*   dst     = (const int*)d_in[3];
    const int*   ety     = (const int*)d_in[4];
    const int*   gid     = (const int*)d_in[5];
    const float* rel_emb = (const float*)d_in[6];
    const float* W_in    = (const float*)d_in[7];
    const float* b_in    = (const float*)d_in[8];
    const float* V       = (const float*)d_in[9];
    const float* comp    = (const float*)d_in[10];
    const float* W_loop  = (const float*)d_in[11];
    const float* b_loop  = (const float*)d_in[12];
    const float* W_attn  = (const float*)d_in[13];
    const float* b_attn  = (const float*)d_in[14];
    const float* w_sc    = (const float*)d_in[15];
    const float* b_sc    = (const float*)d_in[16];
    const float* w_out   = (const float*)d_in[17];
    const float* b_out   = (const float*)d_in[18];
    float* out = (float*)d_out;

    float* ws = (float*)d_ws;
    float* h0 = ws;                                   // 6.4M floats
    float* h1 = h0 + (size_t)N_NODES * HID;           // 6.4M
    float* er = h1 + (size_t)N_NODES * HID;           // 1.6M
    float* af = er + (size_t)N_NODES * REL_DIM;       // 50000
    int* starts    = (int*)(af + N_NODES);            // 260
    int* deg       = starts + 260;                    // 50000
    int* row_start = deg + 50000;                     // 50004
    int* cursor    = row_start + 50004;               // 50000
    int* bsum      = cursor + 50000;                  // 256
    int* boff      = bsum + 256;                      // 256
    int* edge_p    = boff + 256;                      // 800000 packed ints
    unsigned short* Bf = (unsigned short*)(edge_p + 800000);  // 2*36*8*64*16 ushort
    const size_t BF_USHORT = (size_t)NUM_LAYERS * 36 * 8 * 64 * 16;
    unsigned short* Ghi = Bf + BF_USHORT;

    size_t used_floats = (size_t)((float*)Ghi - ws);
    size_t total_floats = ws_size / sizeof(float);
    size_t avail = (total_floats > used_floats) ? (total_floats - used_floats) : 0;
    long long NC = (long long)(avail / 1024);         // rows: 1024 hi + 1024 lo ushorts = 1024 floats
    NC = (NC / 64) * 64;
    if (NC > 50048) NC = 50048;
    if (NC < 64) NC = 64;
    unsigned short* Glo = Ghi + (size_t)NC * 1024;

    // --- preprocessing ---
    k_zero<<<(12500 + 255) / 256, 256, 0, stream>>>((float*)deg, 12500);
    k_hist<<<(N_EDGES + 255) / 256, 256, 0, stream>>>(dst, deg);
    k_scan_a<<<SCAN_BLKS, 256, 0, stream>>>(deg, row_start, bsum);
    k_scan_b<<<1, 256, 0, stream>>>(bsum, boff);
    k_scan_c<<<SCAN_BLKS, 256, 0, stream>>>(row_start, boff, cursor);
    k_scatter<<<(N_EDGES + 255) / 256, 256, 0, stream>>>(src, dst, ety, cursor, edge_p);
    k_bfrag<<<(NUM_LAYERS * 36 * 8 * 64 + 255) / 256, 256, 0, stream>>>(V, W_loop, Bf);
    k_input<<<N_NODES / 16, 128, 0, stream>>>(feat, qrel, rel_emb, W_in, b_in, h0, er);

    float* hcur = h0;
    float* hnext = h1;
    for (int l = 0; l < NUM_LAYERS; l++) {
        const float* comp_l = comp + (size_t)l * NUM_RELS * NUM_BASES;
        const unsigned short* Bfl = Bf + (size_t)l * 36 * 8 * 64 * 16;
        const float* bl = b_loop + (size_t)l * HID;
        for (int c0 = 0; c0 < N_NODES; c0 += (int)NC) {
            int nc = (int)((N_NODES - c0 < NC) ? (N_NODES - c0) : NC);
            k_mix2<<<(nc + 3) / 4, 256, 0, stream>>>(hcur, comp_l, row_start, edge_p,
                                                     Ghi, Glo, c0, nc);
            k_gemm5<<<(nc + 31) / 32, 256, 0, stream>>>(Ghi, Glo, hcur, Bfl, bl,
                                                        hnext, c0, nc);
        }
        float* tmp = hcur; hcur = hnext; hnext = tmp;
    }

    k_score<<<N_NODES / 16, 128, 0, stream>>>(hcur, er, W_attn, b_attn, w_sc, b_sc, af);
    k_starts<<<1, 256, 0, stream>>>(gid, starts);
    k_pool<<<NUM_GRAPHS, 128, 0, stream>>>(hcur, af, starts, w_out, b_out, out);
}